// Round 3
// baseline (3125.023 us; speedup 1.0000x reference)
//
#include <hip/hip_runtime.h>
#include <hip/hip_fp16.h>
#include <cstdint>
#include <cstddef>

#define L_SEQ 2046      // subsampled sequence length
#define NBATCH 32
#define HID 256
#define M_PAD 65536     // padded row count (l2*32+n), 65472 real rows

typedef _Float16 h2vec  __attribute__((ext_vector_type(2)));
typedef _Float16 half8v __attribute__((ext_vector_type(8)));
typedef float    f32x4  __attribute__((ext_vector_type(4)));

static __device__ __forceinline__ uint32_t pack2(float a, float b) {
  __half2 h = __floats2half2_rn(a, b);
  return __builtin_bit_cast(uint32_t, h);
}

static __device__ __forceinline__ float fdot2u(uint32_t w, uint32_t h, float c) {
#if __has_builtin(__builtin_amdgcn_fdot2)
  return __builtin_amdgcn_fdot2(__builtin_bit_cast(h2vec, w),
                                __builtin_bit_cast(h2vec, h), c, false);
#else
  __half2 a = __builtin_bit_cast(__half2, w);
  __half2 b = __builtin_bit_cast(__half2, h);
  float2 fa = __half22float2(a), fb = __half22float2(b);
  return c + fa.x * fb.x + fa.y * fb.y;
#endif
}

static __device__ __forceinline__ void gload_lds16(const void* g, void* l) {
  __builtin_amdgcn_global_load_lds(
      (const __attribute__((address_space(1))) void*)g,
      (__attribute__((address_space(3))) void*)l, 16, 0, 0);
}

// ---- fused conv1 + im2col(for conv2 at even positions), output f16 ----
__global__ void k_conv_im2col(const float* __restrict__ X,
                              const float* __restrict__ W1,
                              const float* __restrict__ b1,
                              __half* __restrict__ A1h) {
  int j   = threadIdx.x;     // 0..383
  int row = blockIdx.x;      // 0..65535
  int l2 = row >> 5, n = row & 31;
  float v = 0.f;
  if (l2 < L_SEQ) {
    int ci = j / 3;
    int k  = j - 3 * ci;
    int p  = 2 * l2 + k;
    const float* xb = X + (size_t)n * 13 * 4096 + p;
    const float* w  = W1 + ci * 39;
    float acc = b1[ci];
#pragma unroll
    for (int c = 0; c < 13; c++) {
      const float* xp = xb + (size_t)c * 4096;
      acc += xp[0] * w[3*c+0] + xp[1] * w[3*c+1] + xp[2] * w[3*c+2];
    }
    v = acc;
  }
  A1h[(size_t)row * 384 + j] = __float2half(v);
}

// ---- f32 -> f16 elementwise (weight pre-convert) ----
__global__ void k_cvt_h(const float* __restrict__ src, __half* __restrict__ dst,
                        int nelem) {
  int i = blockIdx.x * 256 + threadIdx.x;
  if (i < nelem) dst[i] = __float2half(src[i]);
}

// ---- MFMA GEMM: C_f16[M][ldC](+col_off) = A_f16[M][K] @ B_f16[N][K]^T + bias
// 128x128 tile, BK=64, 4 waves (2x2), each wave 64x64 out via 4x4 frags of
// 16x16x32_f16.  Staging: global_load_lds 16B with pre-swizzled SOURCE
// addresses (rule 21): LDS slot s=row*8+c holds (row, ko=c^(row&7)) so the
// swizzled ds_read_b128 is bank-conflict-light while the LDS dest of
// global_load_lds stays linear.
__global__ __launch_bounds__(256, 3) void k_gemm_mfma(
    const __half* __restrict__ A, const __half* __restrict__ Bh,
    const float* __restrict__ bias, __half* __restrict__ C,
    int K, int ldC, int col_off) {
  __shared__ __half Asl[128 * 64];   // 16 KiB
  __shared__ __half Bsl[128 * 64];   // 16 KiB
  const int tid  = threadIdx.x;
  const int wave = tid >> 6, lane = tid & 63;
  const int m_blk = blockIdx.x * 128;
  const int n_blk = blockIdx.y * 128;
  const int wm = wave >> 1, wn = wave & 1;

  f32x4 acc[4][4];
#pragma unroll
  for (int i = 0; i < 4; i++)
#pragma unroll
    for (int j = 0; j < 4; j++) acc[i][j] = (f32x4)0.f;

  // staging geometry: issue i stages slot s = (i*4+wave)*64 + lane
  int srow[4], sko[4];
#pragma unroll
  for (int i = 0; i < 4; i++) {
    int s = (i * 4 + wave) * 64 + lane;
    srow[i] = s >> 3;
    sko[i]  = (s & 7) ^ ((s >> 3) & 7);
  }

  for (int kc = 0; kc < K; kc += 64) {
#pragma unroll
    for (int i = 0; i < 4; i++) {
      int s = (i * 4 + wave) * 64 + lane;
      gload_lds16(A + (size_t)(m_blk + srow[i]) * K + kc + sko[i] * 8,
                  &Asl[s * 8]);
    }
#pragma unroll
    for (int i = 0; i < 4; i++) {
      int s = (i * 4 + wave) * 64 + lane;
      gload_lds16(Bh + (size_t)(n_blk + srow[i]) * K + kc + sko[i] * 8,
                  &Bsl[s * 8]);
    }
    __syncthreads();   // compiler drains vmcnt(0) before s_barrier
#pragma unroll
    for (int kb = 0; kb < 2; kb++) {
      half8v af[4], bf[4];
#pragma unroll
      for (int mi = 0; mi < 4; mi++) {
        int row = wm * 64 + mi * 16 + (lane & 15);
        int c   = (kb * 4 + (lane >> 4)) ^ (row & 7);
        af[mi] = *(const half8v*)&Asl[row * 64 + c * 8];
      }
#pragma unroll
      for (int ni = 0; ni < 4; ni++) {
        int row = wn * 64 + ni * 16 + (lane & 15);
        int c   = (kb * 4 + (lane >> 4)) ^ (row & 7);
        bf[ni] = *(const half8v*)&Bsl[row * 64 + c * 8];
      }
#pragma unroll
      for (int mi = 0; mi < 4; mi++)
#pragma unroll
        for (int ni = 0; ni < 4; ni++)
          acc[mi][ni] = __builtin_amdgcn_mfma_f32_16x16x32_f16(
              af[mi], bf[ni], acc[mi][ni], 0, 0, 0);
    }
    __syncthreads();
  }
  // epilogue: D[m=(lane>>4)*4+r][n=lane&15] per fragment
#pragma unroll
  for (int ni = 0; ni < 4; ni++) {
    int col = wn * 64 + ni * 16 + (lane & 15);
    float bj = bias[n_blk + col];
#pragma unroll
    for (int mi = 0; mi < 4; mi++) {
      int row0 = m_blk + wm * 64 + mi * 16 + (lane >> 4) * 4;
#pragma unroll
      for (int r = 0; r < 4; r++) {
        C[(size_t)(row0 + r) * ldC + col_off + n_blk + col] =
            __float2half(acc[mi][ni][r] + bj);
      }
    }
  }
}

// ---- pre-pack Whh (both dirs) to f16 for the row-per-thread GRU ----
// Consumer thread j (0..767) owns gate-row j, needs Whh[dir][j][0..255] as 32
// packed-f16 uint4.  Layout: Wpk[d*24576 + w*768 + j] = quad w of row j
// (elements 8w..8w+7) -> per-w loads are coalesced across j.
__global__ void k_packw2(const float* __restrict__ Whh_f,
                         const float* __restrict__ Whh_b,
                         uint4* __restrict__ Wpk) {
  int idx = blockIdx.x * 256 + threadIdx.x;   // 0..49151
  int d   = idx / 24576;
  int r   = idx - d * 24576;
  int w   = r / 768;         // 0..31  (k-quad)
  int j   = r - w * 768;     // 0..767 (gate row)
  const float* W = d ? Whh_b : Whh_f;
  const float* src = W + (size_t)j * 256 + w * 8;
  uint4 o;
  o.x = pack2(src[0], src[1]);
  o.y = pack2(src[2], src[3]);
  o.z = pack2(src[4], src[5]);
  o.w = pack2(src[6], src[7]);
  Wpk[(size_t)idx] = o;
}

// ---- GRU recurrence v8: one gate-row per thread ----
// 64 blocks = (dir,n); 768 threads (12 waves, 3 waves/SIMD -> ~170-reg budget).
// Thread j computes the full 256-dot for gate-row j each step: 32 weight quads
// (128 VGPRs) register-resident, h read as 32 BROADCAST ds_read_b128 (no
// swizzle, no bank conflicts, no cross-lane reduce).  Gate recombination via
// a_lds[768] + barrier; activation on waves {0,3,6,9} (one per SIMD under
// either wave->SIMD mapping).  Two barriers/step.
__global__ __attribute__((amdgpu_flat_work_group_size(768, 768),
                          amdgpu_waves_per_eu(3, 3)))
void k_gru(
    const __half* __restrict__ gih, const uint4* __restrict__ Wpk,
    const float* __restrict__ bhh_f, const float* __restrict__ bhh_b,
    float* __restrict__ outF, __half* __restrict__ outBh,
    float* __restrict__ hT) {
  const int blk = blockIdx.x;
  const int dir = blk >> 5;    // 0 fwd, 1 bwd
  const int n   = blk & 31;
  const int tid = threadIdx.x;              // == gate-row j
  const int wv_ = tid >> 6;
  const int lane = tid & 63;
  const bool is_act = (wv_ % 3) == 0;       // waves 0,3,6,9
  const int g = (wv_ / 3) * 64 + lane;      // act channel, 0..255

  const float* bhh = dir ? bhh_b : bhh_f;

  // coalesced load of this thread's 32 weight quads (row tid)
  uint4 wv[32];
  {
    const uint4* wp = Wpk + (size_t)dir * 24576 + tid;
#pragma unroll
    for (int w = 0; w < 32; w++) wv[w] = wp[w * 768];
#pragma unroll
    for (int w = 0; w < 32; w++) {
      asm volatile("" : "+v"(wv[w].x), "+v"(wv[w].y), "+v"(wv[w].z), "+v"(wv[w].w));
    }
  }
  const float bh0 = bhh[g];
  const float bh1 = bhh[256 + g];
  const float bh2 = bhh[512 + g];

  __shared__ __align__(16) __half hs[2][256];   // plain layout, double-buffered
  __shared__ float a_lds[768];
  if (tid < 128) ((uint32_t*)hs)[tid] = 0u;     // zero hs[0]
  float hp = 0.f;

  const __half* gr = gih + ((size_t)(dir ? (size_t)(L_SEQ - 1) * NBATCH : 0) + n) * 1536
                         + dir * 768 + g;
  const ptrdiff_t gstep = dir ? -(ptrdiff_t)(NBATCH * 1536) : (ptrdiff_t)(NBATCH * 1536);
  __half pi0 = __float2half(0.f), pi1 = pi0, pi2 = pi0;
  if (is_act) { pi0 = gr[0]; pi1 = gr[256]; pi2 = gr[512]; }
  __syncthreads();

  for (int t = 0; t < L_SEQ; t++) {
    const uint4* hb = (const uint4*)hs[t & 1];
    float a = 0.f;
#pragma unroll
    for (int w = 0; w < 32; w++) {
      uint4 hq = hb[w];                 // broadcast read, conflict-free
      uint4 u  = wv[w];
      a = fdot2u(u.x, hq.x, a);
      a = fdot2u(u.y, hq.y, a);
      a = fdot2u(u.z, hq.z, a);
      a = fdot2u(u.w, hq.w, a);
    }
    a_lds[tid] = a;
    __syncthreads();                    // a_lds complete

    if (is_act) {
      float hr = a_lds[g]       + bh0;
      float hz = a_lds[256 + g] + bh1;
      float hn = a_lds[512 + g] + bh2;
      float ir  = __half2float(pi0);
      float iz  = __half2float(pi1);
      float inn = __half2float(pi2);
      float rr = 1.f / (1.f + __expf(-(ir + hr)));
      float zz = 1.f / (1.f + __expf(-(iz + hz)));
      float e  = __expf(2.f * (inn + rr * hn));
      float nn = 1.f - 2.f / (e + 1.f);      // tanh, safe at +/-inf
      float hnew = (1.f - zz) * nn + zz * hp;
      hp = hnew;
      __half hh = __float2half(hnew);
      hs[(t + 1) & 1][g] = hh;
      const int l = dir ? (L_SEQ - 1 - t) : t;
      uint32_t oi = ((uint32_t)l * NBATCH + n) * HID + g;
      if (dir == 0) outF[oi] = hnew;
      else          outBh[oi] = hh;
      gr += gstep;
      if (t + 1 < L_SEQ) { pi0 = gr[0]; pi1 = gr[256]; pi2 = gr[512]; }
    }
    __syncthreads();                    // h(t+1) visible
  }
  if (dir == 1 && is_act) hT[n * HID + g] = hp;
}

// ---- combine (in place over outF/d_out): relu(0.5*(out_f + out_b[...,::-1]))
__global__ void k_combine(float* __restrict__ outF,
                          const __half* __restrict__ outBh) {
  int idx = blockIdx.x * 256 + threadIdx.x;
  int c = idx & 255;
  float v = 0.5f * (outF[idx] + __half2float(outBh[idx + 255 - 2 * c]));
  outF[idx] = v > 0.f ? v : 0.f;
}

extern "C" void kernel_launch(void* const* d_in, const int* in_sizes, int n_in,
                              void* d_out, int out_size, void* d_ws, size_t ws_size,
                              hipStream_t stream) {
  const float* X     = (const float*)d_in[0];
  const float* W1    = (const float*)d_in[1];
  const float* b1    = (const float*)d_in[2];
  const float* W2    = (const float*)d_in[3];
  const float* b2    = (const float*)d_in[4];
  const float* Wih_f = (const float*)d_in[5];
  const float* Whh_f = (const float*)d_in[6];
  const float* bih_f = (const float*)d_in[7];
  const float* bhh_f = (const float*)d_in[8];
  const float* Wih_b = (const float*)d_in[9];
  const float* Whh_b = (const float*)d_in[10];
  const float* bih_b = (const float*)d_in[11];
  const float* bhh_b = (const float*)d_in[12];

  // Workspace (bytes), max footprint 251,658,240 (proven to fit):
  //   gih   : [0, 201326592)           65536 x 1536 halves (written by gemm2/3)
  //   W2h   : [0, 196608)              alias in gih region; live only for gemm1
  //   A1h   : [201326592, 251658240)   65536 x 384 halves; DEAD after gemm1
  //   outBh : [201326592, 234848256)   alias (written by k_gru)
  //   Wpk   : [234848768, 235635200)   2 x 24576 uint4, written AFTER gemm1
  //   WihfH : [235635200, 236028416)   768x256 f16, written AFTER gemm1
  //   WihbH : [236028416, 236421632)   768x256 f16, written AFTER gemm1
  char* wsb = (char*)d_ws;
  __half* gih   = (__half*)(wsb);
  __half* W2h   = (__half*)(wsb);
  __half* A1h   = (__half*)(wsb + 201326592);
  __half* outBh = (__half*)(wsb + 201326592);
  uint4*  Wpk   = (uint4*)(wsb + 234848768);
  __half* WihfH = (__half*)(wsb + 235635200);
  __half* WihbH = (__half*)(wsb + 236028416);

  float*  outF  = (float*)d_out;
  __half* xsubh = (__half*)d_out;                      // scratch in d_out
  float*  hT    = outF + (size_t)L_SEQ * NBATCH * HID;

  k_conv_im2col<<<dim3(M_PAD), 384, 0, stream>>>(X, W1, b1, A1h);
  k_cvt_h<<<dim3(384), 256, 0, stream>>>(W2, W2h, 98304);
  k_gemm_mfma<<<dim3(512, 2), 256, 0, stream>>>(A1h, W2h, b2, xsubh, 384, 256, 0);
  // A1h dead; Wpk/WihH regions free now, W2h dead (gih region reused below)
  k_cvt_h<<<dim3(768), 256, 0, stream>>>(Wih_f, WihfH, 196608);
  k_cvt_h<<<dim3(768), 256, 0, stream>>>(Wih_b, WihbH, 196608);
  k_packw2<<<dim3(192), 256, 0, stream>>>(Whh_f, Whh_b, Wpk);
  k_gemm_mfma<<<dim3(512, 6), 256, 0, stream>>>(xsubh, WihfH, bih_f, gih, 256, 1536, 0);
  k_gemm_mfma<<<dim3(512, 6), 256, 0, stream>>>(xsubh, WihbH, bih_b, gih, 256, 1536, 768);
  k_gru<<<dim3(64), 768, 0, stream>>>(gih, Wpk, bhh_f, bhh_b, outF, outBh, hT);
  k_combine<<<dim3(65472), 256, 0, stream>>>(outF, outBh);
}